// Round 3
// baseline (159.212 us; speedup 1.0000x reference)
//
#include <hip/hip_runtime.h>

// Length regulator: out[b, p, :] = att_out[b, idx(b,p), :] for p < total[b], else 0.
// idx(b,p) = upper_bound(csum[b], p), csum = cumsum(round(duration*alpha)).
//
// B=32, L=256, D=512, MAX_LEN=2048. Output 128 MB fp32 -> pure write-stream.
//
// v4 = v3 with the compile fix: __builtin_nontemporal_store requires a NATIVE
// vector type, not HIP's float4 class -> use ext_vector_type(4) throughout the
// copy path.
//
// v3 design notes (v2 was ~70us kernel, ~2 TB/s vs fill's 6.6 TB/s):
//  - THE FIX: two-phase copy (all 16 loads -> sched_barrier -> all 16 stores).
//    vmcnt is one in-order counter over loads AND stores; an interleaved
//    load/store schedule makes every load-use wait on the previous store's
//    HBM completion -> per-wave store pipelining collapses. Load-all/store-all
//    means stores never gate loads (final stores gate nothing).
//  - nontemporal stores: output is write-once; nt keeps att_out L2-resident
//    (2 MB per XCD after the remap) instead of being evicted by the 128 MB
//    write stream.
//  - all-zero fast path: mean(total) ~ L*4 = 1024 = MAX_LEN/2, so ~half the
//    blocks are pure zero-fill: no search, no loads, no dependencies.
//  - kept from v2: shfl wave scan (2 barriers), hoisted per-block idx_tab,
//    XCD-aware remap (lin%8 = XCD, 4 whole batches per XCD).

constexpr int B = 32;
constexpr int L = 256;
constexpr int D = 512;            // floats per row = 128 fvec4
constexpr int MAX_LEN = 2048;
constexpr int POS = 32;           // output positions per block
constexpr int THREADS = 256;      // 2 rows in flight (128 fvec4 lanes per row)

typedef float fvec4 __attribute__((ext_vector_type(4)));

__global__ __launch_bounds__(THREADS) void length_regulator_kernel(
    const float* __restrict__ att_out,   // (B, L, D)
    const float* __restrict__ duration,  // (B, L)
    const int*   __restrict__ alpha_p,   // scalar
    float*       __restrict__ out)       // (B, MAX_LEN, D)
{
    __shared__ int csum[L];
    __shared__ int idx_tab[POS];
    __shared__ int wsum[4];

    const int tid  = threadIdx.x;
    const int lane = tid & 63;
    const int wave = tid >> 6;

    // XCD-aware remap: linear id round-robins over 8 XCDs; give each XCD 4
    // whole batches so its gather reads L2-fit. 2048 % 8 == 0 -> bijective.
    const int lin      = blockIdx.y * gridDim.x + blockIdx.x;   // 0..2047
    const int xcd      = lin & 7;
    const int slot     = lin >> 3;                              // 0..255
    const int b        = xcd * (B / 8) + (slot >> 6);           // 4 batches/XCD
    const int pos_base = (slot & 63) * POS;

    const float alpha = (float)alpha_p[0];

    // ---- cumsum of r = round-half-even(duration*alpha): shfl scan, 2 barriers
    int x = (int)rintf(duration[b * L + tid] * alpha);
    #pragma unroll
    for (int off = 1; off < 64; off <<= 1) {
        int y = __shfl_up(x, off);
        x += (lane >= off) ? y : 0;
    }
    if (lane == 63) wsum[wave] = x;
    __syncthreads();
    const int w0 = wsum[0], w1 = wsum[1], w2 = wsum[2], w3 = wsum[3];
    const int total = w0 + w1 + w2 + w3;
    const int woff = (wave > 0 ? w0 : 0) + (wave > 1 ? w1 : 0) + (wave > 2 ? w2 : 0);
    csum[tid] = x + woff;
    __syncthreads();

    const int lane_r = tid & 127;
    const int rowsel = tid >> 7;          // 0 or 1

    fvec4* __restrict__ dst4 =
        (fvec4*)(out + ((size_t)b * MAX_LEN + pos_base) * D);

    // ---- all-zero fast path: ~half the blocks (mean total ~ MAX_LEN/2) ----
    if (pos_base >= total) {
        const fvec4 z = (fvec4){0.f, 0.f, 0.f, 0.f};
        #pragma unroll
        for (int i = 0; i < POS; i += 2) {
            __builtin_nontemporal_store(
                z, &dst4[(size_t)(i + rowsel) * (D / 4) + lane_r]);
        }
        return;
    }

    // ---- per-block idx table: 32 branchless searches, done ONCE ----
    if (tid < POS) {
        const int p = pos_base + tid;
        int lo = 0;                       // upper_bound = count of csum[] <= p
        #pragma unroll
        for (int step = 128; step >= 1; step >>= 1) {
            const int nxt = lo + step;
            if (nxt <= L && csum[nxt - 1] <= p) lo = nxt;
        }
        idx_tab[tid] = min(lo, L - 1);    // clamp (covers p >= total too)
    }
    __syncthreads();

    const fvec4* __restrict__ src4 = (const fvec4*)(att_out + (size_t)b * L * D);

    // ---- phase 1: ALL gather loads into registers (no stores yet) ----
    fvec4 v[POS / 2];
    #pragma unroll
    for (int i = 0; i < POS; i += 2) {
        const int srow = idx_tab[i + rowsel];             // broadcast LDS read
        v[i / 2] = src4[(size_t)srow * (D / 4) + lane_r]; // clamped, in-bounds
    }
    // Keep every store after every load in the vmcnt stream.
    __builtin_amdgcn_sched_barrier(0);

    // ---- phase 2: ALL stores (nontemporal) ----
    if (pos_base + POS <= total) {
        // fully-kept block: no masking needed
        #pragma unroll
        for (int i = 0; i < POS; i += 2) {
            __builtin_nontemporal_store(
                v[i / 2], &dst4[(size_t)(i + rowsel) * (D / 4) + lane_r]);
        }
    } else {
        // mixed block: mask tail positions to zero
        #pragma unroll
        for (int i = 0; i < POS; i += 2) {
            const int rp = i + rowsel;
            const bool keep = (pos_base + rp) < total;   // wave-uniform
            const fvec4 t = v[i / 2];
            const fvec4 val = keep ? t : (fvec4){0.f, 0.f, 0.f, 0.f};
            __builtin_nontemporal_store(
                val, &dst4[(size_t)rp * (D / 4) + lane_r]);
        }
    }
}

extern "C" void kernel_launch(void* const* d_in, const int* in_sizes, int n_in,
                              void* d_out, int out_size, void* d_ws, size_t ws_size,
                              hipStream_t stream) {
    const float* att_out  = (const float*)d_in[0];
    const float* duration = (const float*)d_in[1];
    const int*   alpha    = (const int*)d_in[2];
    float*       out      = (float*)d_out;

    dim3 grid(MAX_LEN / POS, B);   // (64, 32) = 2048 blocks = 256 CUs x 8 resident
    dim3 block(THREADS);
    length_regulator_kernel<<<grid, block, 0, stream>>>(att_out, duration, alpha, out);
}